// Round 5
// baseline (3274.235 us; speedup 1.0000x reference)
//
#include <hip/hip_runtime.h>
#include <math.h>

#define B 1024
#define N 2048
#define M 128
#define C 512
#define OD (M + 6)
#define EPSF 1e-8f
#define CHUNK 256
#define NCHUNK 8           // N / CHUNK
#define NGRP 32            // concurrent b-groups
#define GRID_F (NCHUNK * NGRP)   // 256 blocks = 1 per CU
#define ITERS (B / NGRP)   // 32 b's per group
#define AGENT __HIP_MEMORY_SCOPE_AGENT

__device__ __forceinline__ float softplusf(float x) {
    return fmaxf(x, 0.f) + log1pf(expf(-fabsf(x)));
}
__device__ __forceinline__ float sigmoidf_(float x) {
    return 1.f / (1.f + expf(-x));
}

// Kernel 1: o = x @ W.T + b; k (first M cols) + scalar head params.
__global__ __launch_bounds__(256) void k_head(
    const float* __restrict__ x, const float* __restrict__ W,
    const float* __restrict__ bias, float* __restrict__ kbuf,
    float* __restrict__ params)
{
    const int b = blockIdx.x;
    __shared__ float xs[C];
    __shared__ float os[OD];
    __shared__ float red[128];

    for (int i = threadIdx.x; i < C; i += 256) xs[i] = x[(size_t)b * C + i];
    __syncthreads();

    if (threadIdx.x < OD) {
        const int j = threadIdx.x;
        const float4* wr = (const float4*)(W + (size_t)j * C);
        float acc = 0.f;
#pragma unroll 8
        for (int c = 0; c < C / 4; ++c) {
            float4 wv = wr[c];
            acc = fmaf(wv.x, xs[4 * c + 0], acc);
            acc = fmaf(wv.y, xs[4 * c + 1], acc);
            acc = fmaf(wv.z, xs[4 * c + 2], acc);
            acc = fmaf(wv.w, xs[4 * c + 3], acc);
        }
        os[j] = acc + bias[j];
    }
    __syncthreads();

    if (threadIdx.x < M) {
        float v = os[threadIdx.x];
        kbuf[(size_t)b * M + threadIdx.x] = v;
        red[threadIdx.x] = v * v;
    }
    __syncthreads();
    for (int s = 64; s > 0; s >>= 1) {
        if (threadIdx.x < s) red[threadIdx.x] += red[threadIdx.x + s];
        __syncthreads();
    }
    if (threadIdx.x == 0) {
        float kn = sqrtf(red[0]);
        float beta = softplusf(os[M]);
        float g = sigmoidf_(os[M + 1]);
        float a0 = os[M + 2], a1 = os[M + 3], a2 = os[M + 4];
        float mx = fmaxf(a0, fmaxf(a1, a2));
        float e0 = expf(a0 - mx), e1 = expf(a1 - mx), e2 = expf(a2 - mx);
        float inv = 1.f / (e0 + e1 + e2);
        float gamma = 1.f + softplusf(os[M + 5]);
        float* p = params + (size_t)b * 8;
        p[0] = beta; p[1] = g; p[2] = e0 * inv; p[3] = e1 * inv;
        p[4] = e2 * inv; p[5] = gamma; p[6] = kn; p[7] = 0.f;
    }
}

// Single-mem-pass fused kernel. 256 persistent blocks (1/CU), 1024 threads.
// Block (bgrp, cid) owns chunk cid (256 rows) of b = bgrp*ITERS + it.
// Chunk held in registers (8 float4/thread) across two device-scope
// spin-syncs per b (S = sum exp(z); T = sum w_t^gamma + r-partials).
// mem is read exactly once. exp without max-subtract: |z| <= beta <= ~9.
__global__ __launch_bounds__(1024) void k_fused(
    const float* __restrict__ mem, const float* __restrict__ kbuf,
    const float* __restrict__ params, const float* __restrict__ w_prev,
    float* __restrict__ w_out, float* __restrict__ r_out,
    float* __restrict__ sPart, float* __restrict__ tPart,
    int* __restrict__ cnt1, int* __restrict__ cnt2,
    float* __restrict__ edgeE, float* __restrict__ rpart, int guard)
{
    __shared__ float eA[CHUNK];
    __shared__ float wgA[CHUNK + 2];
    __shared__ float pwA[CHUNK];
    __shared__ float redA[16 * 128];
    __shared__ float partS[32];
    __shared__ float bcast[2];
    __shared__ float ldspad[18000];   // 72 KB: forces 1 block/CU (residency guarantee)

    const int tid  = threadIdx.x;
    const int lane = tid & 63;
    const int wid  = tid >> 6;       // 0..15
    const int half = lane >> 5;
    const int l32  = lane & 31;
    const int hw   = wid * 2 + half; // 0..31 half-wave id
    const int cid  = blockIdx.x & (NCHUNK - 1);
    const int bgrp = blockIdx.x >> 3;

    if (guard) ldspad[tid] = 0.f;    // never true at runtime; keeps alloc

    float4 frag[8], pfrag[8];
    float4 kv, pkv, p0, p1, pp0, pp1;

    // prologue loads for first b
    {
        const int b0 = bgrp * ITERS;
        const float* cb = mem + ((size_t)b0 * N + cid * CHUNK) * M;
#pragma unroll
        for (int j = 0; j < 8; ++j)
            frag[j] = ((const float4*)(cb + (size_t)(j * 32 + hw) * M))[l32];
        kv = ((const float4*)(kbuf + (size_t)b0 * M))[l32];
        p0 = ((const float4*)(params + (size_t)b0 * 8))[0];
        p1 = ((const float4*)(params + (size_t)b0 * 8))[1];
    }

    for (int it = 0; it < ITERS; ++it) {
        const int b = bgrp * ITERS + it;

        // issue w_prev loads early (consumed in phase B; latency hides)
        float wp_t = 0.f, wpL = 0.f, wpR = 0.f;
        if (tid < CHUNK)
            wp_t = w_prev[(size_t)b * N + cid * CHUNK + tid];
        if (tid == 0) {
            wpL = w_prev[(size_t)b * N + ((cid * CHUNK + N - 1) & (N - 1))];
            wpR = w_prev[(size_t)b * N + ((cid * CHUNK + CHUNK) & (N - 1))];
        }

        const float beta = p0.x, kn = p1.z;

        // ---- phase A: e = exp(beta * cos_sim) for my 8 rows ----
        float myS = 0.f;
#pragma unroll
        for (int j = 0; j < 8; ++j) {
            float dot = frag[j].x * kv.x + frag[j].y * kv.y + frag[j].z * kv.z + frag[j].w * kv.w;
            float sq  = frag[j].x * frag[j].x + frag[j].y * frag[j].y + frag[j].z * frag[j].z + frag[j].w * frag[j].w;
#pragma unroll
            for (int mk = 16; mk >= 1; mk >>= 1) {
                dot += __shfl_xor(dot, mk, 64);
                sq  += __shfl_xor(sq,  mk, 64);
            }
            if (l32 == 0) {
                const float zz = beta * dot / (sqrtf(sq) * kn + EPSF);
                const float e  = expf(zz);
                eA[j * 32 + hw] = e;
                myS += e;
                if (j == 0 && hw == 0)
                    __hip_atomic_store(&edgeE[((size_t)b * 8 + cid) * 2 + 0], e, __ATOMIC_RELEASE, AGENT);
                if (j == 7 && hw == 31)
                    __hip_atomic_store(&edgeE[((size_t)b * 8 + cid) * 2 + 1], e, __ATOMIC_RELEASE, AGENT);
            }
        }
        if (l32 == 0) partS[hw] = myS;
        __syncthreads();

        // ---- prefetch next chunk (flies across the syncs below) ----
        const bool havenext = (it + 1 < ITERS);
        if (havenext) {
            const int bn = b + 1;
            const float* nb = mem + ((size_t)bn * N + cid * CHUNK) * M;
#pragma unroll
            for (int j = 0; j < 8; ++j)
                pfrag[j] = ((const float4*)(nb + (size_t)(j * 32 + hw) * M))[l32];
            pkv = ((const float4*)(kbuf + (size_t)bn * M))[l32];
            pp0 = ((const float4*)(params + (size_t)bn * 8))[0];
            pp1 = ((const float4*)(params + (size_t)bn * 8))[1];
        }

        // ---- sync 1: global S over the 8 peer chunks ----
        if (tid == 0) {
            float S = 0.f;
            for (int h = 0; h < 32; ++h) S += partS[h];
            __hip_atomic_store(&sPart[(size_t)b * 8 + cid], S, __ATOMIC_RELEASE, AGENT);
            __hip_atomic_fetch_add(&cnt1[b], 1, __ATOMIC_RELEASE, AGENT);
            int tries = 0;
            while (__hip_atomic_load(&cnt1[b], __ATOMIC_ACQUIRE, AGENT) < NCHUNK) {
                __builtin_amdgcn_s_sleep(4);
                if (++tries > (1 << 20)) break;   // bailout: fail loud, not hang
            }
            float St = 0.f;
            for (int c2 = 0; c2 < NCHUNK; ++c2)   // fixed order -> deterministic
                St += __hip_atomic_load(&sPart[(size_t)b * 8 + c2], __ATOMIC_RELAXED, AGENT);
            bcast[0] = 1.f / St;
        }
        __syncthreads();

        // ---- phase B: wg, conv3, pow, partial T ----
        const float invS = bcast[0];
        const float g = p0.y, s0p = p0.z, s1p = p0.w, s2p = p1.x, gamma = p1.y;
        if (tid < CHUNK) {
            wgA[tid + 1] = g * eA[tid] * invS + (1.f - g) * wp_t;
            if (tid == 0) {
                const float eL = __hip_atomic_load(&edgeE[((size_t)b * 8 + ((cid + 7) & 7)) * 2 + 1], __ATOMIC_ACQUIRE, AGENT);
                wgA[0] = g * eL * invS + (1.f - g) * wpL;
                const float eR = __hip_atomic_load(&edgeE[((size_t)b * 8 + ((cid + 1) & 7)) * 2 + 0], __ATOMIC_ACQUIRE, AGENT);
                wgA[CHUNK + 1] = g * eR * invS + (1.f - g) * wpR;
            }
        }
        __syncthreads();
        float myT = 0.f;
        if (tid < CHUNK) {
            const float wt = s0p * wgA[tid] + s1p * wgA[tid + 1] + s2p * wgA[tid + 2];
            const float pw = powf(wt, gamma);
            pwA[tid] = pw;
            myT = pw;
        }
#pragma unroll
        for (int mk = 32; mk >= 1; mk >>= 1) myT += __shfl_xor(myT, mk, 64);
        if (lane == 0) partS[wid] = myT;
        __syncthreads();
        if (tid == 0) {
            float T = 0.f;
            for (int w2 = 0; w2 < 16; ++w2) T += partS[w2];
            __hip_atomic_store(&tPart[(size_t)b * 8 + cid], T, __ATOMIC_RELEASE, AGENT);
        }
        __syncthreads();   // pwA visible

        // ---- phase C: UNNORMALIZED r partial from register-held chunk ----
        float4 acc = make_float4(0.f, 0.f, 0.f, 0.f);
#pragma unroll
        for (int j = 0; j < 8; ++j) {
            const float pw = pwA[j * 32 + hw];
            acc.x = fmaf(pw, frag[j].x, acc.x);
            acc.y = fmaf(pw, frag[j].y, acc.y);
            acc.z = fmaf(pw, frag[j].z, acc.z);
            acc.w = fmaf(pw, frag[j].w, acc.w);
        }
        acc.x += __shfl_xor(acc.x, 32, 64);
        acc.y += __shfl_xor(acc.y, 32, 64);
        acc.z += __shfl_xor(acc.z, 32, 64);
        acc.w += __shfl_xor(acc.w, 32, 64);
        if (half == 0) *(float4*)&redA[wid * 128 + l32 * 4] = acc;
        __syncthreads();
        if (tid < 128) {
            float s = 0.f;
#pragma unroll
            for (int w2 = 0; w2 < 16; ++w2) s += redA[w2 * 128 + tid];
            __hip_atomic_store(&rpart[((size_t)b * 8 + cid) * 128 + tid], s, __ATOMIC_RELEASE, AGENT);
        }
        __syncthreads();   // barrier drains the release stores (vmcnt 0)

        // ---- sync 2: T ready + all rpart written ----
        if (tid == 0) {
            __hip_atomic_fetch_add(&cnt2[b], 1, __ATOMIC_RELEASE, AGENT);
            int tries = 0;
            while (__hip_atomic_load(&cnt2[b], __ATOMIC_ACQUIRE, AGENT) < NCHUNK) {
                __builtin_amdgcn_s_sleep(4);
                if (++tries > (1 << 20)) break;
            }
            float T = 0.f;
            for (int c2 = 0; c2 < NCHUNK; ++c2)
                T += __hip_atomic_load(&tPart[(size_t)b * 8 + c2], __ATOMIC_RELAXED, AGENT);
            bcast[1] = 1.f / (T + 1e-16f);
        }
        __syncthreads();

        // ---- phase D: write w slice; cid 0 reduces r ----
        const float invT = bcast[1];
        if (tid < CHUNK)
            w_out[(size_t)b * N + cid * CHUNK + tid] = pwA[tid] * invT;
        if (cid == 0 && tid < 128) {
            float s = 0.f;
#pragma unroll
            for (int c2 = 0; c2 < NCHUNK; ++c2)   // fixed order -> deterministic
                s += __hip_atomic_load(&rpart[((size_t)b * 8 + c2) * 128 + tid], __ATOMIC_RELAXED, AGENT);
            r_out[(size_t)b * M + tid] = s * invT;
        }

        if (havenext) {
#pragma unroll
            for (int j = 0; j < 8; ++j) frag[j] = pfrag[j];
            kv = pkv; p0 = pp0; p1 = pp1;
        }
    }
}

extern "C" void kernel_launch(void* const* d_in, const int* in_sizes, int n_in,
                              void* d_out, int out_size, void* d_ws, size_t ws_size,
                              hipStream_t stream) {
    const float* x      = (const float*)d_in[0];
    const float* w_prev = (const float*)d_in[1];
    const float* mem    = (const float*)d_in[2];
    const float* W      = (const float*)d_in[3];
    const float* bias   = (const float*)d_in[4];

    float* r_out = (float*)d_out;                 // B*M
    float* w_out = (float*)d_out + (size_t)B * M; // B*N

    float* ws     = (float*)d_ws;
    float* kbuf   = ws;                                  // B*M
    float* params = kbuf + (size_t)B * M;                // B*8
    float* sPart  = params + (size_t)B * 8;              // B*8
    float* tPart  = sPart + (size_t)B * 8;               // B*8
    int*   cnt1   = (int*)(tPart + (size_t)B * 8);       // B ints
    int*   cnt2   = cnt1 + B;                            // B ints
    float* edgeE  = (float*)(cnt2 + B);                  // B*8*2
    float* rpart  = edgeE + (size_t)B * 16;              // B*8*128

    // counters must be zero every call (ws is poisoned once, never restored)
    hipMemsetAsync(cnt1, 0, 2 * B * sizeof(int), stream);

    k_head<<<B, 256, 0, stream>>>(x, W, bias, kbuf, params);
    k_fused<<<GRID_F, 1024, 0, stream>>>(mem, kbuf, params, w_prev, w_out, r_out,
                                         sPart, tPart, cnt1, cnt2, edgeE, rpart, 0);
}

// Round 6
// 433.195 us; speedup vs baseline: 7.5583x; 7.5583x over previous
//
#include <hip/hip_runtime.h>
#include <math.h>

#define B 1024
#define N 2048
#define M 128
#define C 512
#define OD (M + 6)
#define EPSF 1e-8f
#define CHUNK 256
#define NCHUNK 8
#define NGRP 32
#define ITERS 32
#define GRID_F 256
#define AGENT __HIP_MEMORY_SCOPE_AGENT

typedef unsigned int u32;

__device__ __forceinline__ float softplusf(float x) {
    return fmaxf(x, 0.f) + log1pf(expf(-fabsf(x)));
}
__device__ __forceinline__ float sigmoidf_(float x) {
    return 1.f / (1.f + expf(-x));
}

// async global->LDS, 16B per lane; lds dest = wave-uniform base + lane*16
__device__ __forceinline__ void g2lds16(const float* gsrc, float* ldst) {
    __builtin_amdgcn_global_load_lds(
        (const __attribute__((address_space(1))) u32*)gsrc,
        (__attribute__((address_space(3))) u32*)ldst, 16, 0, 0);
}

// LDS-only barrier: no vmcnt drain (prefetch stays in flight)
__device__ __forceinline__ void bar_lds() {
    asm volatile("s_waitcnt lgkmcnt(0)" ::: "memory");
    __builtin_amdgcn_s_barrier();
}

// Kernel 1: o = x @ W.T + b; k (first M cols) + scalar head params.
__global__ __launch_bounds__(256) void k_head(
    const float* __restrict__ x, const float* __restrict__ W,
    const float* __restrict__ bias, float* __restrict__ kbuf,
    float* __restrict__ params)
{
    const int b = blockIdx.x;
    __shared__ float xs[C];
    __shared__ float os[OD];
    __shared__ float red[128];

    for (int i = threadIdx.x; i < C; i += 256) xs[i] = x[(size_t)b * C + i];
    __syncthreads();

    if (threadIdx.x < OD) {
        const int j = threadIdx.x;
        const float4* wr = (const float4*)(W + (size_t)j * C);
        float acc = 0.f;
#pragma unroll 8
        for (int c = 0; c < C / 4; ++c) {
            float4 wv = wr[c];
            acc = fmaf(wv.x, xs[4 * c + 0], acc);
            acc = fmaf(wv.y, xs[4 * c + 1], acc);
            acc = fmaf(wv.z, xs[4 * c + 2], acc);
            acc = fmaf(wv.w, xs[4 * c + 3], acc);
        }
        os[j] = acc + bias[j];
    }
    __syncthreads();

    if (threadIdx.x < M) {
        float v = os[threadIdx.x];
        kbuf[(size_t)b * M + threadIdx.x] = v;
        red[threadIdx.x] = v * v;
    }
    __syncthreads();
    for (int s = 64; s > 0; s >>= 1) {
        if (threadIdx.x < s) red[threadIdx.x] += red[threadIdx.x + s];
        __syncthreads();
    }
    if (threadIdx.x == 0) {
        float kn = sqrtf(red[0]);
        float beta = softplusf(os[M]);
        float g = sigmoidf_(os[M + 1]);
        float a0 = os[M + 2], a1 = os[M + 3], a2 = os[M + 4];
        float mx = fmaxf(a0, fmaxf(a1, a2));
        float e0 = expf(a0 - mx), e1 = expf(a1 - mx), e2 = expf(a2 - mx);
        float inv = 1.f / (e0 + e1 + e2);
        float gamma = 1.f + softplusf(os[M + 5]);
        float* p = params + (size_t)b * 8;
        p[0] = beta; p[1] = g; p[2] = e0 * inv; p[3] = e1 * inv;
        p[4] = e2 * inv; p[5] = gamma; p[6] = kn; p[7] = 0.f;
    }
}

// Single-mem-pass fused kernel v2. 256 blocks (1/CU, LDS-bound), 512 threads.
// Block (bgrp = blockIdx&31, cid = blockIdx>>5): peers of a b share bgrp ->
// same blockIdx%8 -> same XCD (heuristic). Chunk staged in LDS via
// global_load_lds (per-wave own region), consumed from registers.
// ONE relaxed-atomic sync per b (softmax denom S + edge e's); T and final
// normalization deferred to k_norm. exp without max-subtract: |z|<=beta<=~9.
__global__ __launch_bounds__(512, 2) void k_fused(
    const float* __restrict__ mem, const float* __restrict__ kbuf,
    const float* __restrict__ params, const float* __restrict__ w_prev,
    float* __restrict__ w_out,
    float* __restrict__ sPart, float* __restrict__ tPart,
    int* __restrict__ cnt1, float* __restrict__ edgeE,
    float* __restrict__ rpart)
{
    __shared__ float stage[CHUNK * M];   // 128 KB staging
    __shared__ float eA[CHUNK];
    __shared__ float wgA[CHUNK + 2];
    __shared__ float pwA[CHUNK];
    __shared__ float redA[8 * 128];
    __shared__ float partS[16];
    __shared__ float partT[8];
    __shared__ float bcast[4];

    const int tid  = threadIdx.x;
    const int lane = tid & 63;
    const int wv   = tid >> 6;       // 0..7
    const int half = lane >> 5;
    const int l32  = lane & 31;
    const int hw   = wv * 2 + half;  // 0..15

    const int bgrp = blockIdx.x & 31;
    const int cid  = blockIdx.x >> 5;

    float4 kv, pkv, p0, p1, pp0, pp1;

    // prologue: stage chunk of first b + its params
    {
        const int b0 = bgrp * ITERS;
        kv = ((const float4*)(kbuf + (size_t)b0 * M))[l32];
        p0 = ((const float4*)(params + (size_t)b0 * 8))[0];
        p1 = ((const float4*)(params + (size_t)b0 * 8))[1];
        const float* cb = mem + ((size_t)b0 * N + cid * CHUNK + wv * 32) * M;
        float* ld = stage + wv * 32 * M;
#pragma unroll
        for (int k = 0; k < 16; ++k)
            g2lds16(cb + k * 256 + lane * 4, ld + k * 256);
    }

    for (int it = 0; it < ITERS; ++it) {
        const int b = bgrp * ITERS + it;

        // wait own wave's staged region (per-wave; no block barrier needed)
        asm volatile("s_waitcnt vmcnt(0)" ::: "memory");
        __builtin_amdgcn_sched_barrier(0);
        float4 frag[16];
#pragma unroll
        for (int j = 0; j < 16; ++j)
            frag[j] = ((const float4*)stage)[(hw * 16 + j) * 32 + l32];

        const float beta = p0.x, kn = p1.z;

        // ---- phase A: e = exp(beta * cos_sim) for my 16 rows ----
        float myS = 0.f;
#pragma unroll
        for (int j = 0; j < 16; ++j) {
            float dot = frag[j].x * kv.x + frag[j].y * kv.y + frag[j].z * kv.z + frag[j].w * kv.w;
            float sq  = frag[j].x * frag[j].x + frag[j].y * frag[j].y + frag[j].z * frag[j].z + frag[j].w * frag[j].w;
#pragma unroll
            for (int s = 16; s >= 1; s >>= 1) {
                dot += __shfl_xor(dot, s, 64);
                sq  += __shfl_xor(sq,  s, 64);
            }
            if (l32 == 0) {
                const float z = beta * dot / (sqrtf(sq) * kn + EPSF);
                const float e = expf(z);
                eA[hw * 16 + j] = e;
                myS += e;
            }
        }
        if (l32 == 0) partS[hw] = myS;
        bar_lds();   // barrier 1: eA/partS visible

        // ---- publish S_c + edge e's, arrive (relaxed; one vmcnt ack) ----
        if (tid == 0) {
            float S = 0.f;
#pragma unroll
            for (int h = 0; h < 16; ++h) S += partS[h];
            __hip_atomic_store(&sPart[(size_t)b * 8 + cid], S, __ATOMIC_RELAXED, AGENT);
            __hip_atomic_store(&edgeE[((size_t)b * 8 + cid) * 2 + 0], eA[0], __ATOMIC_RELAXED, AGENT);
            __hip_atomic_store(&edgeE[((size_t)b * 8 + cid) * 2 + 1], eA[CHUNK - 1], __ATOMIC_RELAXED, AGENT);
            asm volatile("s_waitcnt vmcnt(0)" ::: "memory");
            __hip_atomic_fetch_add(&cnt1[b], 1, __ATOMIC_RELAXED, AGENT);
        }

        // ---- issue small loads FIRST (so their wait won't drain prefetch) ----
        float wp_t = 0.f, wpL = 0.f, wpR = 0.f;
        if (tid < CHUNK)
            wp_t = w_prev[(size_t)b * N + cid * CHUNK + tid];
        if (tid == 0) {
            wpL = w_prev[(size_t)b * N + ((cid * CHUNK + N - 1) & (N - 1))];
            wpR = w_prev[(size_t)b * N + ((cid * CHUNK + CHUNK) & (N - 1))];
        }
        const bool havenext = (it + 1 < ITERS);
        if (havenext) {
            const int bn = b + 1;
            pkv = ((const float4*)(kbuf + (size_t)bn * M))[l32];
            pp0 = ((const float4*)(params + (size_t)bn * 8))[0];
            pp1 = ((const float4*)(params + (size_t)bn * 8))[1];
            // ---- async prefetch of next chunk (flies across spin + phases) ----
            const float* nb = mem + ((size_t)bn * N + cid * CHUNK + wv * 32) * M;
            float* ld = stage + wv * 32 * M;
#pragma unroll
            for (int k = 0; k < 16; ++k)
                g2lds16(nb + k * 256 + lane * 4, ld + k * 256);
        }

        // ---- spin (relaxed polls only; no cache maintenance) ----
        if (tid == 0) {
            int tries = 0;
            while (__hip_atomic_load(&cnt1[b], __ATOMIC_RELAXED, AGENT) < NCHUNK) {
                __builtin_amdgcn_s_sleep(2);
                if (++tries > (1 << 22)) break;   // failsafe: fail loud, not hang
            }
            float St = 0.f;
#pragma unroll
            for (int c2 = 0; c2 < NCHUNK; ++c2)   // fixed order -> deterministic
                St += __hip_atomic_load(&sPart[(size_t)b * 8 + c2], __ATOMIC_RELAXED, AGENT);
            bcast[0] = 1.f / St;
            bcast[1] = __hip_atomic_load(&edgeE[((size_t)b * 8 + ((cid + 7) & 7)) * 2 + 1], __ATOMIC_RELAXED, AGENT);
            bcast[2] = __hip_atomic_load(&edgeE[((size_t)b * 8 + ((cid + 1) & 7)) * 2 + 0], __ATOMIC_RELAXED, AGENT);
        }
        bar_lds();   // barrier 2: bcast visible (raw barrier: prefetch unaffected)

        // ---- phase B: wg, conv3, pow, partial T ----
        const float invS = bcast[0], eL = bcast[1], eR = bcast[2];
        const float g = p0.y, s0p = p0.z, s1p = p0.w, s2p = p1.x, gamma = p1.y;
        if (tid < CHUNK)
            wgA[tid + 1] = g * eA[tid] * invS + (1.f - g) * wp_t;
        if (tid == 0) {
            wgA[0]         = g * eL * invS + (1.f - g) * wpL;
            wgA[CHUNK + 1] = g * eR * invS + (1.f - g) * wpR;
        }
        bar_lds();   // barrier 3: wgA visible

        float myT = 0.f;
        if (tid < CHUNK) {
            const float wt = s0p * wgA[tid] + s1p * wgA[tid + 1] + s2p * wgA[tid + 2];
            const float pw = powf(wt, gamma);
            pwA[tid] = pw;
            myT = pw;
        }
#pragma unroll
        for (int s = 32; s >= 1; s >>= 1) myT += __shfl_xor(myT, s, 64);
        if (lane == 0) partT[wv] = myT;
        bar_lds();   // barrier 4: pwA/partT visible

        if (tid == 0) {
            float T = 0.f;
#pragma unroll
            for (int w2 = 0; w2 < 8; ++w2) T += partT[w2];
            tPart[(size_t)b * 8 + cid] = T;   // plain store; k_norm boundary syncs
        }

        // ---- phase C: unnormalized r partial from register-held chunk ----
        float4 acc = make_float4(0.f, 0.f, 0.f, 0.f);
#pragma unroll
        for (int j = 0; j < 16; ++j) {
            const float pw = pwA[hw * 16 + j];
            acc.x = fmaf(pw, frag[j].x, acc.x);
            acc.y = fmaf(pw, frag[j].y, acc.y);
            acc.z = fmaf(pw, frag[j].z, acc.z);
            acc.w = fmaf(pw, frag[j].w, acc.w);
        }
        acc.x += __shfl_xor(acc.x, 32, 64);
        acc.y += __shfl_xor(acc.y, 32, 64);
        acc.z += __shfl_xor(acc.z, 32, 64);
        acc.w += __shfl_xor(acc.w, 32, 64);
        if (half == 0) *(float4*)&redA[wv * 128 + l32 * 4] = acc;
        bar_lds();   // barrier 5: redA visible

        if (tid < 128) {
            float s = 0.f;
#pragma unroll
            for (int w2 = 0; w2 < 8; ++w2) s += redA[w2 * 128 + tid];
            rpart[((size_t)b * 8 + cid) * 128 + tid] = s;   // plain store
        }
        // ---- phase D: unnormalized w slice (k_norm scales in place) ----
        if (tid < CHUNK)
            w_out[(size_t)b * N + cid * CHUNK + tid] = pwA[tid];

        if (havenext) { kv = pkv; p0 = pp0; p1 = pp1; }
    }
}

// Tiny epilogue: per b, T = sum of 8 chunk partials; scale w in place; reduce r.
__global__ __launch_bounds__(256) void k_norm(
    const float* __restrict__ tPart, const float* __restrict__ rpart,
    float* __restrict__ w_out, float* __restrict__ r_out)
{
    const int b = blockIdx.x, tid = threadIdx.x;
    float T = 0.f;
#pragma unroll
    for (int c = 0; c < 8; ++c) T += tPart[(size_t)b * 8 + c];   // fixed order
    const float invT = 1.f / (T + 1e-16f);

    float4* w4 = (float4*)(w_out + (size_t)b * N);
#pragma unroll
    for (int k = 0; k < 2; ++k) {
        float4 v = w4[tid + k * 256];
        v.x *= invT; v.y *= invT; v.z *= invT; v.w *= invT;
        w4[tid + k * 256] = v;
    }
    if (tid < 128) {
        float s = 0.f;
#pragma unroll
        for (int c = 0; c < 8; ++c)   // fixed order -> deterministic
            s += rpart[((size_t)b * 8 + c) * 128 + tid];
        r_out[(size_t)b * M + tid] = s * invT;
    }
}

extern "C" void kernel_launch(void* const* d_in, const int* in_sizes, int n_in,
                              void* d_out, int out_size, void* d_ws, size_t ws_size,
                              hipStream_t stream) {
    const float* x      = (const float*)d_in[0];
    const float* w_prev = (const float*)d_in[1];
    const float* mem    = (const float*)d_in[2];
    const float* W      = (const float*)d_in[3];
    const float* bias   = (const float*)d_in[4];

    float* r_out = (float*)d_out;                 // B*M
    float* w_out = (float*)d_out + (size_t)B * M; // B*N

    float* ws     = (float*)d_ws;
    float* kbuf   = ws;                                  // B*M
    float* params = kbuf + (size_t)B * M;                // B*8
    float* sPart  = params + (size_t)B * 8;              // B*8
    float* tPart  = sPart + (size_t)B * 8;               // B*8
    int*   cnt1   = (int*)(tPart + (size_t)B * 8);       // B ints
    float* edgeE  = (float*)(cnt1 + B);                  // B*8*2
    float* rpart  = edgeE + (size_t)B * 16;              // B*8*128

    // arrival counters must be zero every call
    hipMemsetAsync(cnt1, 0, B * sizeof(int), stream);

    k_head<<<B, 256, 0, stream>>>(x, W, bias, kbuf, params);
    k_fused<<<GRID_F, 512, 0, stream>>>(mem, kbuf, params, w_prev, w_out,
                                        sPart, tPart, cnt1, edgeE, rpart);
    k_norm<<<B, 256, 0, stream>>>(tPart, rpart, w_out, r_out);
}

// Round 7
// 344.818 us; speedup vs baseline: 9.4956x; 1.2563x over previous
//
#include <hip/hip_runtime.h>
#include <math.h>

#define B 1024
#define N 2048
#define M 128
#define C 512
#define OD (M + 6)
#define EPSF 1e-8f
#define CHUNK 512
#define NCHUNK 4           // N / CHUNK
#define NGRP 64            // concurrent b-groups
#define ITERS (B / NGRP)   // 16
#define GRID_F (NCHUNK * NGRP)   // 256 blocks = 1/CU
#define AGENT __HIP_MEMORY_SCOPE_AGENT

__device__ __forceinline__ float softplusf(float x) {
    return fmaxf(x, 0.f) + log1pf(expf(-fabsf(x)));
}
__device__ __forceinline__ float sigmoidf_(float x) {
    return 1.f / (1.f + expf(-x));
}

// LDS-only barrier (no vmcnt drain)
__device__ __forceinline__ void bar_lds() {
    asm volatile("s_waitcnt lgkmcnt(0)" ::: "memory");
    __builtin_amdgcn_s_barrier();
}

// Kernel 1: o = x @ W.T + b; k (first M cols) + scalar head params.
__global__ __launch_bounds__(256) void k_head(
    const float* __restrict__ x, const float* __restrict__ W,
    const float* __restrict__ bias, float* __restrict__ kbuf,
    float* __restrict__ params)
{
    const int b = blockIdx.x;
    __shared__ float xs[C];
    __shared__ float os[OD];
    __shared__ float red[128];

    for (int i = threadIdx.x; i < C; i += 256) xs[i] = x[(size_t)b * C + i];
    __syncthreads();

    if (threadIdx.x < OD) {
        const int j = threadIdx.x;
        const float4* wr = (const float4*)(W + (size_t)j * C);
        float acc = 0.f;
#pragma unroll 8
        for (int c = 0; c < C / 4; ++c) {
            float4 wv = wr[c];
            acc = fmaf(wv.x, xs[4 * c + 0], acc);
            acc = fmaf(wv.y, xs[4 * c + 1], acc);
            acc = fmaf(wv.z, xs[4 * c + 2], acc);
            acc = fmaf(wv.w, xs[4 * c + 3], acc);
        }
        os[j] = acc + bias[j];
    }
    __syncthreads();

    if (threadIdx.x < M) {
        float v = os[threadIdx.x];
        kbuf[(size_t)b * M + threadIdx.x] = v;
        red[threadIdx.x] = v * v;
    }
    __syncthreads();
    for (int s = 64; s > 0; s >>= 1) {
        if (threadIdx.x < s) red[threadIdx.x] += red[threadIdx.x + s];
        __syncthreads();
    }
    if (threadIdx.x == 0) {
        float kn = sqrtf(red[0]);
        float beta = softplusf(os[M]);
        float g = sigmoidf_(os[M + 1]);
        float a0 = os[M + 2], a1 = os[M + 3], a2 = os[M + 4];
        float mx = fmaxf(a0, fmaxf(a1, a2));
        float e0 = expf(a0 - mx), e1 = expf(a1 - mx), e2 = expf(a2 - mx);
        float inv = 1.f / (e0 + e1 + e2);
        float gamma = 1.f + softplusf(os[M + 5]);
        float* p = params + (size_t)b * 8;
        p[0] = beta; p[1] = g; p[2] = e0 * inv; p[3] = e1 * inv;
        p[4] = e2 * inv; p[5] = gamma; p[6] = kn; p[7] = 0.f;
    }
}

// Single-mem-pass fused kernel v3. 256 blocks (1/CU), 1024 threads (16 waves).
// Block (cid = blockIdx/64, bgrp = blockIdx%64) owns chunk cid (512 rows) of
// b = bgrp*16 + it. Chunk loaded straight into registers (16 float4/thread);
// ONE relaxed-atomic sync per b (softmax denom S + chunk-edge e's). T and
// final normalization deferred to k_norm. mem read exactly once.
// exp without max-subtract: |z| <= beta (bounded ~12) -> f32-safe.
__global__ __launch_bounds__(1024, 4) void k_fused(
    const float* __restrict__ mem, const float* __restrict__ kbuf,
    const float* __restrict__ params, const float* __restrict__ w_prev,
    float* __restrict__ w_out,
    float* __restrict__ sPart, float* __restrict__ tPart,
    int* __restrict__ cnt1, float* __restrict__ edgeE,
    float* __restrict__ rpart)
{
    __shared__ float eA[CHUNK];
    __shared__ float wgA[CHUNK + 2];
    __shared__ float pwA[CHUNK];
    __shared__ float redA[16 * 128];
    __shared__ float partS[32];
    __shared__ float partT[8];
    __shared__ float bcast[4];

    const int tid  = threadIdx.x;
    const int lane = tid & 63;
    const int wv   = tid >> 6;       // 0..15
    const int half = lane >> 5;
    const int l32  = lane & 31;
    const int hw   = wv * 2 + half;  // 0..31: half-wave id (16 rows each)

    const int cid  = blockIdx.x >> 6;       // 0..3
    const int bgrp = blockIdx.x & 63;       // peers share bgrp -> same XCD

    for (int it = 0; it < ITERS; ++it) {
        const int b = bgrp * ITERS + it;
        const float* cb = mem + ((size_t)b * N + cid * CHUNK) * M;

        // ---- issue chunk loads (64 MB aggregate burst across the chip) ----
        float4 frag[16];
#pragma unroll
        for (int j = 0; j < 16; ++j)
            frag[j] = ((const float4*)(cb + (size_t)(hw * 16 + j) * M))[l32];

        // small loads issued early; consumed in phase B
        float wp_t = 0.f, wpL = 0.f, wpR = 0.f;
        if (tid < CHUNK)
            wp_t = w_prev[(size_t)b * N + cid * CHUNK + tid];
        if (tid == 0) {
            wpL = w_prev[(size_t)b * N + ((cid * CHUNK + N - 1) & (N - 1))];
            wpR = w_prev[(size_t)b * N + ((cid * CHUNK + CHUNK) & (N - 1))];
        }
        const float4 kv = ((const float4*)(kbuf + (size_t)b * M))[l32];
        const float4 p0 = ((const float4*)(params + (size_t)b * 8))[0];
        const float4 p1 = ((const float4*)(params + (size_t)b * 8))[1];
        const float beta = p0.x, kn = p1.z;

        // ---- phase A: e = exp(beta * cos_sim) for my 16 rows ----
        float myS = 0.f;
#pragma unroll
        for (int j = 0; j < 16; ++j) {
            float dot = frag[j].x * kv.x + frag[j].y * kv.y + frag[j].z * kv.z + frag[j].w * kv.w;
            float sq  = frag[j].x * frag[j].x + frag[j].y * frag[j].y + frag[j].z * frag[j].z + frag[j].w * frag[j].w;
#pragma unroll
            for (int s = 16; s >= 1; s >>= 1) {
                dot += __shfl_xor(dot, s, 64);
                sq  += __shfl_xor(sq,  s, 64);
            }
            if (l32 == 0) {
                const float z = beta * dot / (sqrtf(sq) * kn + EPSF);
                const float e = expf(z);
                eA[hw * 16 + j] = e;
                myS += e;
            }
        }
        if (l32 == 0) partS[hw] = myS;
        bar_lds();   // barrier 1: eA/partS visible

        // ---- publish S_c + edge e's, arrive, spin (all relaxed) ----
        if (tid == 0) {
            float S = 0.f;
#pragma unroll
            for (int h = 0; h < 32; ++h) S += partS[h];
            __hip_atomic_store(&sPart[(size_t)b * NCHUNK + cid], S, __ATOMIC_RELAXED, AGENT);
            __hip_atomic_store(&edgeE[((size_t)b * NCHUNK + cid) * 2 + 0], eA[0], __ATOMIC_RELAXED, AGENT);
            __hip_atomic_store(&edgeE[((size_t)b * NCHUNK + cid) * 2 + 1], eA[CHUNK - 1], __ATOMIC_RELAXED, AGENT);
            asm volatile("s_waitcnt vmcnt(0)" ::: "memory");
            __hip_atomic_fetch_add(&cnt1[b], 1, __ATOMIC_RELAXED, AGENT);
            int tries = 0;
            while (__hip_atomic_load(&cnt1[b], __ATOMIC_RELAXED, AGENT) < NCHUNK) {
                __builtin_amdgcn_s_sleep(1);
                if (++tries > (1 << 22)) break;   // failsafe: fail loud, not hang
            }
            float St = 0.f;
#pragma unroll
            for (int c2 = 0; c2 < NCHUNK; ++c2)   // fixed order -> deterministic
                St += __hip_atomic_load(&sPart[(size_t)b * NCHUNK + c2], __ATOMIC_RELAXED, AGENT);
            bcast[0] = 1.f / St;
            bcast[1] = __hip_atomic_load(&edgeE[((size_t)b * NCHUNK + ((cid + NCHUNK - 1) & (NCHUNK - 1))) * 2 + 1], __ATOMIC_RELAXED, AGENT);
            bcast[2] = __hip_atomic_load(&edgeE[((size_t)b * NCHUNK + ((cid + 1) & (NCHUNK - 1))) * 2 + 0], __ATOMIC_RELAXED, AGENT);
        }
        bar_lds();   // barrier 2: bcast visible

        // ---- phase B: wg, conv3, pow, partial T ----
        const float invS = bcast[0], eL = bcast[1], eR = bcast[2];
        const float g = p0.y, s0p = p0.z, s1p = p0.w, s2p = p1.x, gamma = p1.y;
        if (tid < CHUNK)
            wgA[tid + 1] = g * eA[tid] * invS + (1.f - g) * wp_t;
        if (tid == 0) {
            wgA[0]         = g * eL * invS + (1.f - g) * wpL;
            wgA[CHUNK + 1] = g * eR * invS + (1.f - g) * wpR;
        }
        bar_lds();   // barrier 3: wgA visible

        float myT = 0.f;
        if (tid < CHUNK) {
            const float wt = s0p * wgA[tid] + s1p * wgA[tid + 1] + s2p * wgA[tid + 2];
            const float pw = powf(wt, gamma);
            pwA[tid] = pw;
            myT = pw;
        }
#pragma unroll
        for (int s = 32; s >= 1; s >>= 1) myT += __shfl_xor(myT, s, 64);
        if (lane == 0 && wv < 8) partT[wv] = myT;
        bar_lds();   // barrier 4: pwA/partT visible

        if (tid == 0) {
            float T = 0.f;
#pragma unroll
            for (int w2 = 0; w2 < 8; ++w2) T += partT[w2];
            tPart[(size_t)b * NCHUNK + cid] = T;   // plain store; kernel boundary syncs
        }

        // ---- phase C: unnormalized r partial from register-held chunk ----
        float4 acc = make_float4(0.f, 0.f, 0.f, 0.f);
#pragma unroll
        for (int j = 0; j < 16; ++j) {
            const float pw = pwA[hw * 16 + j];
            acc.x = fmaf(pw, frag[j].x, acc.x);
            acc.y = fmaf(pw, frag[j].y, acc.y);
            acc.z = fmaf(pw, frag[j].z, acc.z);
            acc.w = fmaf(pw, frag[j].w, acc.w);
        }
        acc.x += __shfl_xor(acc.x, 32, 64);
        acc.y += __shfl_xor(acc.y, 32, 64);
        acc.z += __shfl_xor(acc.z, 32, 64);
        acc.w += __shfl_xor(acc.w, 32, 64);
        if (half == 0) *(float4*)&redA[wv * 128 + l32 * 4] = acc;
        bar_lds();   // barrier 5: redA visible

        if (tid < 128) {
            float s = 0.f;
#pragma unroll
            for (int w2 = 0; w2 < 16; ++w2) s += redA[w2 * 128 + tid];
            rpart[((size_t)b * NCHUNK + cid) * 128 + tid] = s;   // plain store
        }
        // ---- phase D: unnormalized w slice (k_norm scales in place) ----
        if (tid < CHUNK)
            w_out[(size_t)b * N + cid * CHUNK + tid] = pwA[tid];
        // no trailing barrier needed: next iteration's barrier 1 protects LDS
        // (eA rewritten only by the same lanes that wrote it; wgA/pwA rewritten
        // after barrier 2/3 of the next iteration)
        bar_lds();
    }
}

// Tiny epilogue: per b, T = sum of chunk partials; scale w in place; reduce r.
__global__ __launch_bounds__(256) void k_norm(
    const float* __restrict__ tPart, const float* __restrict__ rpart,
    float* __restrict__ w_out, float* __restrict__ r_out)
{
    const int b = blockIdx.x, tid = threadIdx.x;
    float T = 0.f;
#pragma unroll
    for (int c = 0; c < NCHUNK; ++c) T += tPart[(size_t)b * NCHUNK + c];
    const float invT = 1.f / (T + 1e-16f);

    float4* w4 = (float4*)(w_out + (size_t)b * N);
#pragma unroll
    for (int k = 0; k < 2; ++k) {
        float4 v = w4[tid + k * 256];
        v.x *= invT; v.y *= invT; v.z *= invT; v.w *= invT;
        w4[tid + k * 256] = v;
    }
    if (tid < 128) {
        float s = 0.f;
#pragma unroll
        for (int c = 0; c < NCHUNK; ++c)   // fixed order -> deterministic
            s += rpart[((size_t)b * NCHUNK + c) * 128 + tid];
        r_out[(size_t)b * M + tid] = s * invT;
    }
}

extern "C" void kernel_launch(void* const* d_in, const int* in_sizes, int n_in,
                              void* d_out, int out_size, void* d_ws, size_t ws_size,
                              hipStream_t stream) {
    const float* x      = (const float*)d_in[0];
    const float* w_prev = (const float*)d_in[1];
    const float* mem    = (const float*)d_in[2];
    const float* W      = (const float*)d_in[3];
    const float* bias   = (const float*)d_in[4];

    float* r_out = (float*)d_out;                 // B*M
    float* w_out = (float*)d_out + (size_t)B * M; // B*N

    float* ws     = (float*)d_ws;
    float* kbuf   = ws;                                    // B*M
    float* params = kbuf + (size_t)B * M;                  // B*8
    float* sPart  = params + (size_t)B * 8;                // B*NCHUNK
    float* tPart  = sPart + (size_t)B * NCHUNK;            // B*NCHUNK
    int*   cnt1   = (int*)(tPart + (size_t)B * NCHUNK);    // B ints
    float* edgeE  = (float*)(cnt1 + B);                    // B*NCHUNK*2
    float* rpart  = edgeE + (size_t)B * NCHUNK * 2;        // B*NCHUNK*128

    // arrival counters must be zero every call
    hipMemsetAsync(cnt1, 0, B * sizeof(int), stream);

    k_head<<<B, 256, 0, stream>>>(x, W, bias, kbuf, params);
    k_fused<<<GRID_F, 1024, 0, stream>>>(mem, kbuf, params, w_prev, w_out,
                                         sPart, tPart, cnt1, edgeE, rpart);
    k_norm<<<B, 256, 0, stream>>>(tPart, rpart, w_out, r_out);
}